// Round 4
// baseline (261.087 us; speedup 1.0000x reference)
//
#include <hip/hip_runtime.h>
#include <math.h>

// Problem geometry (fixed by setup_inputs)
#define NN 2
#define DD 160
#define HH 192
#define WW 160
#define DO 154   // DD-6
#define HO 186   // HH-6
#define WO 154   // WW-6

#define NWO 3    // wo tiles of 64
#define HOT 8    // ho tile
#define NHO 24   // ceil(186/8)
#define ZCH 7    // z chunks: 154 = 7*22 exactly -> every block nslice=28=4*7
#define ZOC 22
#define NSL 28   // ZOC+6, compile-time constant for ALL blocks
#define NB (NWO * NHO * NN * ZCH)   // 1008 blocks (~3.94/CU)

// LDS-only barrier: s_waitcnt lgkmcnt(0) (vmcnt left outstanding) + s_barrier.
#define LDS_SYNC() do { __builtin_amdgcn_s_waitcnt(0xC07F); __builtin_amdgcn_s_barrier(); } while (0)

__device__ __forceinline__ float block_sum(float v, float* sm) {
  int tid = threadIdx.x;
  sm[tid] = v;
  __syncthreads();
#pragma unroll
  for (int off = 128; off > 0; off >>= 1) {
    if (tid < off) sm[tid] += sm[tid + off];
    __syncthreads();
  }
  float r = sm[0];
  __syncthreads();
  return r;
}

__device__ __forceinline__ float block_min(float v, float* sm) {
  int tid = threadIdx.x;
  sm[tid] = v;
  __syncthreads();
#pragma unroll
  for (int off = 128; off > 0; off >>= 1) {
    if (tid < off) sm[tid] = fminf(sm[tid], sm[tid + off]);
    __syncthreads();
  }
  float r = sm[0];
  __syncthreads();
  return r;
}

__device__ __forceinline__ float wave_sum(float v) {
  v += __shfl_xor(v, 32); v += __shfl_xor(v, 16); v += __shfl_xor(v, 8);
  v += __shfl_xor(v, 4);  v += __shfl_xor(v, 2);  v += __shfl_xor(v, 1);
  return v;
}

__device__ __forceinline__ float wave_min(float v) {
  v = fminf(v, __shfl_xor(v, 32)); v = fminf(v, __shfl_xor(v, 16));
  v = fminf(v, __shfl_xor(v, 8));  v = fminf(v, __shfl_xor(v, 4));
  v = fminf(v, __shfl_xor(v, 2));  v = fminf(v, __shfl_xor(v, 1));
  return v;
}

__device__ __forceinline__ float4 f4add(float4 a, float4 b) {
  return make_float4(a.x + b.x, a.y + b.y, a.z + b.z, a.w + b.w);
}
// m - s + n
__device__ __forceinline__ float4 f4slide(float4 m, float4 s, float4 n) {
  return make_float4(m.x - s.x + n.x, m.y - s.y + n.y, m.z - s.z + n.z, m.w - s.w + n.w);
}

// 7-tap sliding W-sum over 10 inputs -> 4 outputs (one float4 store, dense layout).
#define SLIDE7(V, M) do { \
  float s0 = ((V[0]+V[1])+(V[2]+V[3])) + ((V[4]+V[5])+V[6]); \
  float s1 = s0 - V[0] + V[7]; \
  float s2 = s1 - V[1] + V[8]; \
  float s3 = s2 - V[2] + V[9]; \
  *(float4*)&R[M][rA][c4] = make_float4(s0, s1, s2, s3); \
} while (0)

// Mh row r lives at float-offset ((r&3)*2 + (r>>2)) * 64 from the [ch][0][0][w] base.
#define MOFF(r) (((((r) & 3) << 1) + ((r) >> 2)) << 6)

// (256,3): do NOT tighten to (256,4) — that caps unified VGPR/AGPR at 128 and
// forces the 70-float Z-history ring into scratch (round-2: 31 MB HBM writeback).
__global__ __launch_bounds__(256, 3) void ncc_fused(const float* __restrict__ X,
                                                    const float* __restrict__ Y,
                                                    float* __restrict__ part) {
  __shared__ __align__(16) float R[5][14][64];      // 17.9 KB W-filtered moment rows
  __shared__ __align__(16) float Mh[5][4][2][64];   // 10.2 KB, row r at [ch][r&3][r>>2][w]
  __shared__ float red[4][5];

  const int tid = threadIdx.x;
  const int tx = tid & 63, ty = tid >> 6;
  const int wo0 = blockIdx.x * 64;
  const int ho0 = blockIdx.y * HOT;
  const int n   = blockIdx.z / ZCH;
  const int ck  = blockIdx.z % ZCH;
  const int z0  = ck * ZOC;

  const int wo = wo0 + tx;
  const bool act0 = (wo < WO) && (ho0 + ty < HO);
  const bool act1 = (wo < WO) && (ho0 + ty + 4 < HO);

  const size_t slice = (size_t)HH * WW;
  const float* Xn = X + (size_t)n * DD * slice;
  const float* Yn = Y + (size_t)n * DD * slice;
  const float inv_nw = 1.0f / 343.0f;
  const float LO = -1.0f - 1e-5f, HI = 1.0f + 1e-5f;

  // Phase-A item: 224 items; item p -> row rA=p>>4 (0..13), 4 outputs at cols c4..c4+3.
  const int pA  = tid;
  const bool hasA = (pA < 224);
  const int rA  = pA >> 4;
  const int c4  = (pA & 15) << 2;
  const int hA  = ho0 + rA;
  const int baseW = wo0 + c4;                  // multiple of 4
  const bool okA  = hasA && (hA < HH) && (baseW < WO);
  const bool tail = okA && (baseW + 10 > WW);  // only baseW==152: read 8, zero 2
  const float* XrowA = Xn + (size_t)hA * WW + baseW;
  const float* YrowA = Yn + (size_t)hA * WW + baseW;

  float4 lx0={0,0,0,0}, lx1={0,0,0,0};
  float4 ly0={0,0,0,0}, ly1={0,0,0,0};
  float2 lx2={0,0}, ly2={0,0};

  auto loadA = [&](int s_in) {
    if (okA) {
      const float* xp = XrowA + (size_t)(z0 + s_in) * slice;
      const float* yp = YrowA + (size_t)(z0 + s_in) * slice;
      lx0 = *(const float4*)xp;       lx1 = *(const float4*)(xp + 4);
      ly0 = *(const float4*)yp;       ly1 = *(const float4*)(yp + 4);
      if (!tail) { lx2 = *(const float2*)(xp + 8); ly2 = *(const float2*)(yp + 8); }
      else       { lx2 = make_float2(0.f, 0.f);    ly2 = make_float2(0.f, 0.f); }
    }
  };

  auto storeA = [&]() {
    if (okA) {
      const float x[10] = {lx0.x,lx0.y,lx0.z,lx0.w, lx1.x,lx1.y,lx1.z,lx1.w, lx2.x,lx2.y};
      const float y[10] = {ly0.x,ly0.y,ly0.z,ly0.w, ly1.x,ly1.y,ly1.z,ly1.w, ly2.x,ly2.y};
      SLIDE7(x, 0);
      SLIDE7(y, 1);
      {
        float t[10];
#pragma unroll
        for (int i = 0; i < 10; ++i) t[i] = x[i] * x[i];
        SLIDE7(t, 2);
      }
      {
        float t[10];
#pragma unroll
        for (int i = 0; i < 10; ++i) t[i] = y[i] * y[i];
        SLIDE7(t, 3);
      }
      {
        float t[10];
#pragma unroll
        for (int i = 0; i < 10; ++i) t[i] = x[i] * y[i];
        SLIDE7(t, 4);
      }
    }
  };

  // Phase H (b128): 80 items = (ch 0..4) x (wq 0..15), 20 lanes per wave:
  //   lanes 0..15  -> ch = wave, wq = lane
  //   lanes 16..19 -> ch = 4,    wq = wave*4 + (lane-16)
  // Each item: 14 ds_read_b128 down column group wq of R (immediate offsets off one
  // base), ring-of-7 float4 slide, 8 ds_write_b128 into Mh. Quarter-waves read
  // dense 256-B chunks -> full-BW, no extra conflicts.
  int chH = 0, wqH = 0; bool okH = false;
  if (tx < 16)      { chH = ty; wqH = tx;                    okH = true; }
  else if (tx < 20) { chH = 4;  wqH = (ty << 2) + (tx - 16); okH = true; }
  const float4* colH = (const float4*)&R[chH][0][wqH << 2];  // row step = 16 float4
  float* mhb = &Mh[chH][0][0][wqH << 2];

  auto phaseH = [&]() {
    if (okH) {
      float4 w0 = colH[0],  w1 = colH[16], w2 = colH[32], w3 = colH[48],
             w4 = colH[64], w5 = colH[80], w6 = colH[96];
      float4 m = f4add(f4add(f4add(w0, w1), f4add(w2, w3)), f4add(f4add(w4, w5), w6));
      *(float4*)(mhb + MOFF(0)) = m;
      float4 nw;
      nw = colH[112]; m = f4slide(m, w0, nw); w0 = nw; *(float4*)(mhb + MOFF(1)) = m;
      nw = colH[128]; m = f4slide(m, w1, nw); w1 = nw; *(float4*)(mhb + MOFF(2)) = m;
      nw = colH[144]; m = f4slide(m, w2, nw); w2 = nw; *(float4*)(mhb + MOFF(3)) = m;
      nw = colH[160]; m = f4slide(m, w3, nw); w3 = nw; *(float4*)(mhb + MOFF(4)) = m;
      nw = colH[176]; m = f4slide(m, w4, nw); w4 = nw; *(float4*)(mhb + MOFF(5)) = m;
      nw = colH[192]; m = f4slide(m, w5, nw); w5 = nw; *(float4*)(mhb + MOFF(6)) = m;
      nw = colH[208]; m = f4slide(m, w6, nw); w6 = nw; *(float4*)(mhb + MOFF(7)) = m;
    }
  };

  // Phase-O read base: rows (ty, ty+4) are 64 floats apart -> ds_read2_b32 pairs.
  const float* mhoB = &Mh[0][ty][0][tx];   // ch stride = 512 floats

  // Sliding-window Z accumulation: zs += m_new - hist[u]; hist[u] = m_new.
  // Ring index u is static (loop unrolled by 7) -> stays in registers/AGPRs.
  float zs0[2]={0,0}, zs1[2]={0,0}, zs2[2]={0,0}, zs3[2]={0,0}, zs4[2]={0,0};
  float h0[2][7], h1[2][7], h2[2][7], h3[2][7], h4[2][7];
#pragma unroll
  for (int j = 0; j < 7; ++j) {
    h0[0][j]=0.f; h1[0][j]=0.f; h2[0][j]=0.f; h3[0][j]=0.f; h4[0][j]=0.f;
    h0[1][j]=0.f; h1[1][j]=0.f; h2[1][j]=0.f; h3[1][j]=0.f; h4[1][j]=0.f;
  }
  float p_snv = 0.f, p_sn = 0.f, p_sv = 0.f, p_cnt = 0.f, p_vmin = 3.4e38f;

  loadA(0);
  storeA();
  __syncthreads();

#pragma unroll 1
  for (int sb = 0; sb < NSL; sb += 7) {     // NSL = 28 = 4*7 for EVERY block
#pragma unroll
    for (int u = 0; u < 7; ++u) {
      const int s = sb + u;
      if (s + 1 < NSL) loadA(s + 1);        // global -> regs (stays in flight)
      phaseH();                             // R -> Mh (b128)
      LDS_SYNC();
      {                                     // Phase O: Mh -> sliding-Z + epilogue
        float ma0 = mhoB[0],    mb0 = mhoB[64];
        float ma1 = mhoB[512],  mb1 = mhoB[576];
        float ma2 = mhoB[1024], mb2 = mhoB[1088];
        float ma3 = mhoB[1536], mb3 = mhoB[1600];
        float ma4 = mhoB[2048], mb4 = mhoB[2112];
#pragma unroll
        for (int rb = 0; rb < 2; ++rb) {
          float m0 = rb ? mb0 : ma0, m1 = rb ? mb1 : ma1, m2 = rb ? mb2 : ma2,
                m3 = rb ? mb3 : ma3, m4 = rb ? mb4 : ma4;
          zs0[rb] += m0 - h0[rb][u]; h0[rb][u] = m0;
          zs1[rb] += m1 - h1[rb][u]; h1[rb][u] = m1;
          zs2[rb] += m2 - h2[rb][u]; h2[rb][u] = m2;
          zs3[rb] += m3 - h3[rb][u]; h3[rb][u] = m3;
          zs4[rb] += m4 - h4[rb][u]; h4[rb][u] = m4;
          if (s >= 6 && (rb ? act1 : act0)) {
            float num = zs4[rb] - zs0[rb] * zs1[rb] * inv_nw;
            float d0  = zs2[rb] - zs0[rb] * zs0[rb] * inv_nw;
            float d1  = zs3[rb] - zs1[rb] * zs1[rb] * inv_nw;
            float den = d0 * d1;
            if (den > 1e-5f) {
              float ncc = num * __frsqrt_rn(den);
              if (ncc >= LO && ncc <= HI) {
                float v = 0.5f * (d0 + d1);
                p_snv += ncc * v; p_sn += ncc; p_sv += v; p_cnt += 1.f;
                p_vmin = fminf(p_vmin, v);
              }
            }
          }
        }
      }
      if (s + 1 < NSL) storeA();            // vmcnt wait lands HERE
      LDS_SYNC();
    }
  }

  // Wave-level reduction (6 shfl each), then 4 partials through LDS.
  float r0 = wave_sum(p_snv);
  float r1 = wave_sum(p_sn);
  float r2 = wave_sum(p_sv);
  float r3 = wave_sum(p_cnt);
  float r4 = wave_min(p_vmin);
  if (tx == 0) {
    red[ty][0]=r0; red[ty][1]=r1; red[ty][2]=r2; red[ty][3]=r3; red[ty][4]=r4;
  }
  __syncthreads();
  if (tid == 0) {
    float s0 = (red[0][0]+red[1][0]) + (red[2][0]+red[3][0]);
    float s1 = (red[0][1]+red[1][1]) + (red[2][1]+red[3][1]);
    float s2 = (red[0][2]+red[1][2]) + (red[2][2]+red[3][2]);
    float s3 = (red[0][3]+red[1][3]) + (red[2][3]+red[3][3]);
    float s4 = fminf(fminf(red[0][4],red[1][4]), fminf(red[2][4],red[3][4]));
    const int bid = blockIdx.x + NWO * (blockIdx.y + NHO * blockIdx.z);
    float* pp = part + (size_t)bid * 8;
    pp[0] = s0; pp[1] = s1; pp[2] = s2; pp[3] = s3; pp[4] = s4;
  }
}

// Reduce NB per-block partials; loss = 1 - (S_nv - vmin*S_n)/(S_v - vmin*cnt)
// (the min-max weight scale HIGH/(vmax-vmin+1e-12) cancels in w/sum(w)).
__global__ __launch_bounds__(256) void fin(const float* __restrict__ part,
                                           float* __restrict__ out) {
  __shared__ float sm[256];
  const int tid = threadIdx.x;
  float s0 = 0.f, s1 = 0.f, s2 = 0.f, s3 = 0.f, vm = 3.4e38f;
  for (int b = tid; b < NB; b += 256) {
    const float* pp = part + (size_t)b * 8;
    s0 += pp[0]; s1 += pp[1]; s2 += pp[2]; s3 += pp[3];
    vm = fminf(vm, pp[4]);
  }
  s0 = block_sum(s0, sm);
  s1 = block_sum(s1, sm);
  s2 = block_sum(s2, sm);
  s3 = block_sum(s3, sm);
  vm = block_min(vm, sm);
  if (tid == 0) {
    out[0] = 1.0f - (s0 - vm * s1) / (s2 - vm * s3);
  }
}

extern "C" void kernel_launch(void* const* d_in, const int* in_sizes, int n_in,
                              void* d_out, int out_size, void* d_ws, size_t ws_size,
                              hipStream_t stream) {
  const float* X = (const float*)d_in[0];  // y_pred
  const float* Y = (const float*)d_in[1];  // y_true
  // d_in[2]: ones kernel, constant, unused.

  float* part = (float*)d_ws;  // NB * 8 floats = 31.5 KB

  dim3 g(NWO, NHO, NN * ZCH);
  ncc_fused<<<g, 256, 0, stream>>>(X, Y, part);
  fin<<<1, 256, 0, stream>>>(part, (float*)d_out);
}

// Round 5
// 166.543 us; speedup vs baseline: 1.5677x; 1.5677x over previous
//
#include <hip/hip_runtime.h>
#include <math.h>

// Problem geometry (fixed by setup_inputs)
#define NN 2
#define DD 160
#define HH 192
#define WW 160
#define DO 154   // DD-6
#define HO 186   // HH-6
#define WO 154   // WW-6

#define NWO 3    // wo tiles of 64
#define HOT 8    // ho tile
#define NHO 24   // ceil(186/8)
#define ZCH 7    // z chunks: 154 = 7*22 exactly -> every block nslice=28=4*7
#define ZOC 22
#define NSL 28   // ZOC+6, compile-time constant for ALL blocks
#define NB (NWO * NHO * NN * ZCH)   // 1008 blocks

// LDS-only barrier: s_waitcnt lgkmcnt(0) (vmcnt left outstanding) + s_barrier.
#define LDS_SYNC() do { __builtin_amdgcn_s_waitcnt(0xC07F); __builtin_amdgcn_s_barrier(); } while (0)

__device__ __forceinline__ float block_sum(float v, float* sm) {
  int tid = threadIdx.x;
  sm[tid] = v;
  __syncthreads();
#pragma unroll
  for (int off = 128; off > 0; off >>= 1) {
    if (tid < off) sm[tid] += sm[tid + off];
    __syncthreads();
  }
  float r = sm[0];
  __syncthreads();
  return r;
}

__device__ __forceinline__ float block_min(float v, float* sm) {
  int tid = threadIdx.x;
  sm[tid] = v;
  __syncthreads();
#pragma unroll
  for (int off = 128; off > 0; off >>= 1) {
    if (tid < off) sm[tid] = fminf(sm[tid], sm[tid + off]);
    __syncthreads();
  }
  float r = sm[0];
  __syncthreads();
  return r;
}

__device__ __forceinline__ float wave_sum(float v) {
  v += __shfl_xor(v, 32); v += __shfl_xor(v, 16); v += __shfl_xor(v, 8);
  v += __shfl_xor(v, 4);  v += __shfl_xor(v, 2);  v += __shfl_xor(v, 1);
  return v;
}

__device__ __forceinline__ float wave_min(float v) {
  v = fminf(v, __shfl_xor(v, 32)); v = fminf(v, __shfl_xor(v, 16));
  v = fminf(v, __shfl_xor(v, 8));  v = fminf(v, __shfl_xor(v, 4));
  v = fminf(v, __shfl_xor(v, 2));  v = fminf(v, __shfl_xor(v, 1));
  return v;
}

// 7-tap sliding W-sum over 14 inputs -> 8 outputs (two aligned float4 stores).
#define SLIDE7W8(V, M) do { \
  float s0 = ((V[0]+V[1])+(V[2]+V[3])) + ((V[4]+V[5])+V[6]); \
  float s1 = s0 - V[0] + V[7]; \
  float s2 = s1 - V[1] + V[8]; \
  float s3 = s2 - V[2] + V[9]; \
  float s4 = s3 - V[3] + V[10]; \
  float s5 = s4 - V[4] + V[11]; \
  float s6 = s5 - V[5] + V[12]; \
  float s7 = s6 - V[6] + V[13]; \
  *(float4*)&R[M][rA][c8]     = make_float4(s0, s1, s2, s3); \
  *(float4*)&R[M][rA][c8 + 4] = make_float4(s4, s5, s6, s7); \
} while (0)

// 512 threads = 8 waves; disjoint wave roles:
//   A: tid < 112   (W8 items: rows 0..13 x col-groups 0..7)
//   H: 128 <= tid < 448  (ch = (tid-128)>>6 in 0..4, w = (tid-128)&63)
//   O: all threads, 1 output row each (row = wave)
// (512,2): 256-reg budget -> no spill risk (rounds 2/4 both died on spill).
__global__ __launch_bounds__(512, 2) void ncc_fused(const float* __restrict__ X,
                                                    const float* __restrict__ Y,
                                                    float* __restrict__ part) {
  __shared__ __align__(16) float R[5][14][64];   // 17.9 KB W-filtered moment rows
  __shared__ __align__(16) float Mh[5][HOT][64]; // 10.2 KB W+H-filtered moments
  __shared__ float red[8][5];

  const int tid = threadIdx.x;
  const int tx = tid & 63, wv = tid >> 6;
  const int wo0 = blockIdx.x * 64;
  const int ho0 = blockIdx.y * HOT;
  const int n   = blockIdx.z / ZCH;
  const int ck  = blockIdx.z % ZCH;
  const int z0  = ck * ZOC;

  const int wo = wo0 + tx;
  const bool act = (wo < WO) && (ho0 + wv < HO);

  const size_t slice = (size_t)HH * WW;
  const float* Xn = X + (size_t)n * DD * slice;
  const float* Yn = Y + (size_t)n * DD * slice;
  const float inv_nw = 1.0f / 343.0f;
  const float LO = -1.0f - 1e-5f, HI = 1.0f + 1e-5f;

  // Phase-A item: 112 items; item p -> row rA=p>>3 (0..13), 8 outputs at cols c8..c8+7.
  const int pA  = tid;
  const bool hasA = (pA < 112);
  const int rA  = pA >> 3;
  const int c8  = (pA & 7) << 3;
  const int hA  = ho0 + rA;
  const int baseW = wo0 + c8;                  // multiple of 8
  const bool okA  = hasA && (hA < HH) && (baseW < WO);
  const bool tail = okA && (baseW + 14 > WW);  // only baseW==152: read 8, zero 6
  const float* XrowA = Xn + (size_t)hA * WW + baseW;
  const float* YrowA = Yn + (size_t)hA * WW + baseW;

  float4 lx0={0,0,0,0}, lx1={0,0,0,0}, lx2={0,0,0,0};
  float4 ly0={0,0,0,0}, ly1={0,0,0,0}, ly2={0,0,0,0};
  float2 lx3={0,0}, ly3={0,0};

  auto loadA = [&](int s_in) {
    if (okA) {
      const float* xp = XrowA + (size_t)(z0 + s_in) * slice;
      const float* yp = YrowA + (size_t)(z0 + s_in) * slice;
      lx0 = *(const float4*)xp;       lx1 = *(const float4*)(xp + 4);
      ly0 = *(const float4*)yp;       ly1 = *(const float4*)(yp + 4);
      if (!tail) {
        lx2 = *(const float4*)(xp + 8); lx3 = *(const float2*)(xp + 12);
        ly2 = *(const float4*)(yp + 8); ly3 = *(const float2*)(yp + 12);
      } else {
        lx2 = make_float4(0.f,0.f,0.f,0.f); lx3 = make_float2(0.f,0.f);
        ly2 = make_float4(0.f,0.f,0.f,0.f); ly3 = make_float2(0.f,0.f);
      }
    }
  };

  auto storeA = [&]() {
    if (okA) {
      const float x[14] = {lx0.x,lx0.y,lx0.z,lx0.w, lx1.x,lx1.y,lx1.z,lx1.w,
                           lx2.x,lx2.y,lx2.z,lx2.w, lx3.x,lx3.y};
      const float y[14] = {ly0.x,ly0.y,ly0.z,ly0.w, ly1.x,ly1.y,ly1.z,ly1.w,
                           ly2.x,ly2.y,ly2.z,ly2.w, ly3.x,ly3.y};
      SLIDE7W8(x, 0);
      SLIDE7W8(y, 1);
      {
        float t[14];
#pragma unroll
        for (int i = 0; i < 14; ++i) t[i] = x[i] * x[i];
        SLIDE7W8(t, 2);
      }
      {
        float t[14];
#pragma unroll
        for (int i = 0; i < 14; ++i) t[i] = y[i] * y[i];
        SLIDE7W8(t, 3);
      }
      {
        float t[14];
#pragma unroll
        for (int i = 0; i < 14; ++i) t[i] = x[i] * y[i];
        SLIDE7W8(t, 4);
      }
    }
  };

  // Phase H: 7-tap sliding H-sums, 14 rows -> 8 outputs per (ch, w). 320 items
  // on waves 2..6 (tid 128..447). Sequential consumption keeps live set ~9.
  const int idxH = tid - 128;
  const bool okH = (tid >= 128) && (idxH < 320);
  const int chH = okH ? (idxH >> 6) : 0;
  const int wH  = idxH & 63;
  const float* rpH = &R[chH][0][wH];

  auto phaseH = [&]() {
    if (okH) {
      float w0 = rpH[0],   w1 = rpH[64],  w2 = rpH[128], w3 = rpH[192],
            w4 = rpH[256], w5 = rpH[320], w6 = rpH[384];
      float m = ((w0+w1)+(w2+w3)) + ((w4+w5)+w6);
      Mh[chH][0][wH] = m;
      float nw;
      nw = rpH[448]; m = m - w0 + nw; Mh[chH][1][wH] = m;
      nw = rpH[512]; m = m - w1 + nw; Mh[chH][2][wH] = m;
      nw = rpH[576]; m = m - w2 + nw; Mh[chH][3][wH] = m;
      nw = rpH[640]; m = m - w3 + nw; Mh[chH][4][wH] = m;
      nw = rpH[704]; m = m - w4 + nw; Mh[chH][5][wH] = m;
      nw = rpH[768]; m = m - w5 + nw; Mh[chH][6][wH] = m;
      nw = rpH[832]; m = m - w6 + nw; Mh[chH][7][wH] = m;
    }
  };

  // Sliding-window Z accumulation (single row per thread): 35-float history.
  float zs0=0.f, zs1=0.f, zs2=0.f, zs3=0.f, zs4=0.f;
  float h0[7], h1[7], h2[7], h3[7], h4[7];
#pragma unroll
  for (int j = 0; j < 7; ++j) { h0[j]=0.f; h1[j]=0.f; h2[j]=0.f; h3[j]=0.f; h4[j]=0.f; }
  float p_snv = 0.f, p_sn = 0.f, p_sv = 0.f, p_cnt = 0.f, p_vmin = 3.4e38f;

  loadA(0);
  storeA();
  __syncthreads();

#pragma unroll 1
  for (int sb = 0; sb < NSL; sb += 7) {     // NSL = 28 = 4*7 for EVERY block
#pragma unroll
    for (int u = 0; u < 7; ++u) {
      const int s = sb + u;
      if (s + 1 < NSL) loadA(s + 1);        // global -> regs (stays in flight)
      phaseH();                             // R -> Mh
      LDS_SYNC();
      {                                     // Phase O: Mh -> sliding-Z + epilogue
        float m0 = Mh[0][wv][tx], m1 = Mh[1][wv][tx], m2 = Mh[2][wv][tx],
              m3 = Mh[3][wv][tx], m4 = Mh[4][wv][tx];
        zs0 += m0 - h0[u]; h0[u] = m0;
        zs1 += m1 - h1[u]; h1[u] = m1;
        zs2 += m2 - h2[u]; h2[u] = m2;
        zs3 += m3 - h3[u]; h3[u] = m3;
        zs4 += m4 - h4[u]; h4[u] = m4;
        if (s >= 6 && act) {
          float num = zs4 - zs0 * zs1 * inv_nw;
          float d0  = zs2 - zs0 * zs0 * inv_nw;
          float d1  = zs3 - zs1 * zs1 * inv_nw;
          float den = d0 * d1;
          if (den > 1e-5f) {
            float ncc = num * __frsqrt_rn(den);
            if (ncc >= LO && ncc <= HI) {
              float v = 0.5f * (d0 + d1);
              p_snv += ncc * v; p_sn += ncc; p_sv += v; p_cnt += 1.f;
              p_vmin = fminf(p_vmin, v);
            }
          }
        }
      }
      if (s + 1 < NSL) storeA();            // vmcnt wait lands HERE
      LDS_SYNC();
    }
  }

  // Wave-level reduction (6 shfl each), then 8 partials through LDS.
  float r0 = wave_sum(p_snv);
  float r1 = wave_sum(p_sn);
  float r2 = wave_sum(p_sv);
  float r3 = wave_sum(p_cnt);
  float r4 = wave_min(p_vmin);
  if (tx == 0) {
    red[wv][0]=r0; red[wv][1]=r1; red[wv][2]=r2; red[wv][3]=r3; red[wv][4]=r4;
  }
  __syncthreads();
  if (tid == 0) {
    float s0=0.f, s1=0.f, s2=0.f, s3=0.f, s4=3.4e38f;
#pragma unroll
    for (int w = 0; w < 8; ++w) {
      s0 += red[w][0]; s1 += red[w][1]; s2 += red[w][2]; s3 += red[w][3];
      s4 = fminf(s4, red[w][4]);
    }
    const int bid = blockIdx.x + NWO * (blockIdx.y + NHO * blockIdx.z);
    float* pp = part + (size_t)bid * 8;
    pp[0] = s0; pp[1] = s1; pp[2] = s2; pp[3] = s3; pp[4] = s4;
  }
}

// Reduce NB per-block partials; loss = 1 - (S_nv - vmin*S_n)/(S_v - vmin*cnt)
// (the min-max weight scale HIGH/(vmax-vmin+1e-12) cancels in w/sum(w)).
__global__ __launch_bounds__(256) void fin(const float* __restrict__ part,
                                           float* __restrict__ out) {
  __shared__ float sm[256];
  const int tid = threadIdx.x;
  float s0 = 0.f, s1 = 0.f, s2 = 0.f, s3 = 0.f, vm = 3.4e38f;
  for (int b = tid; b < NB; b += 256) {
    const float* pp = part + (size_t)b * 8;
    s0 += pp[0]; s1 += pp[1]; s2 += pp[2]; s3 += pp[3];
    vm = fminf(vm, pp[4]);
  }
  s0 = block_sum(s0, sm);
  s1 = block_sum(s1, sm);
  s2 = block_sum(s2, sm);
  s3 = block_sum(s3, sm);
  vm = block_min(vm, sm);
  if (tid == 0) {
    out[0] = 1.0f - (s0 - vm * s1) / (s2 - vm * s3);
  }
}

extern "C" void kernel_launch(void* const* d_in, const int* in_sizes, int n_in,
                              void* d_out, int out_size, void* d_ws, size_t ws_size,
                              hipStream_t stream) {
  const float* X = (const float*)d_in[0];  // y_pred
  const float* Y = (const float*)d_in[1];  // y_true
  // d_in[2]: ones kernel, constant, unused.

  float* part = (float*)d_ws;  // NB * 8 floats = 31.5 KB

  dim3 g(NWO, NHO, NN * ZCH);
  ncc_fused<<<g, 512, 0, stream>>>(X, Y, part);
  fin<<<1, 256, 0, stream>>>(part, (float*)d_out);
}

// Round 6
// 165.101 us; speedup vs baseline: 1.5814x; 1.0087x over previous
//
#include <hip/hip_runtime.h>
#include <math.h>

// Problem geometry (fixed by setup_inputs)
#define NN 2
#define DD 160
#define HH 192
#define WW 160
#define DO 154   // DD-6
#define HO 186   // HH-6
#define WO 154   // WW-6

#define NWO 3    // wo tiles of 64
#define HOT 8    // ho tile
#define NHO 24   // ceil(186/8)
#define ZCH 7    // z chunks: 154 = 7*22 exactly -> every block nslice=28=4*7
#define ZOC 22
#define NSL 28   // ZOC+6, compile-time constant for ALL blocks
#define NB (NWO * NHO * NN * ZCH)   // 1008 blocks

#define RP 68    // R row pad: 68 floats (272B) -> storeA b128 bank bases spread
                 // (4*rA + 8*q) mod 32, killing round-5's 2.59M conflicts.

// LDS-only barrier: s_waitcnt lgkmcnt(0) (vmcnt left outstanding) + s_barrier.
#define LDS_SYNC() do { __builtin_amdgcn_s_waitcnt(0xC07F); __builtin_amdgcn_s_barrier(); } while (0)

__device__ __forceinline__ float block_sum(float v, float* sm) {
  int tid = threadIdx.x;
  sm[tid] = v;
  __syncthreads();
#pragma unroll
  for (int off = 128; off > 0; off >>= 1) {
    if (tid < off) sm[tid] += sm[tid + off];
    __syncthreads();
  }
  float r = sm[0];
  __syncthreads();
  return r;
}

__device__ __forceinline__ float block_min(float v, float* sm) {
  int tid = threadIdx.x;
  sm[tid] = v;
  __syncthreads();
#pragma unroll
  for (int off = 128; off > 0; off >>= 1) {
    if (tid < off) sm[tid] = fminf(sm[tid], sm[tid + off]);
    __syncthreads();
  }
  float r = sm[0];
  __syncthreads();
  return r;
}

__device__ __forceinline__ float wave_sum(float v) {
  v += __shfl_xor(v, 32); v += __shfl_xor(v, 16); v += __shfl_xor(v, 8);
  v += __shfl_xor(v, 4);  v += __shfl_xor(v, 2);  v += __shfl_xor(v, 1);
  return v;
}

__device__ __forceinline__ float wave_min(float v) {
  v = fminf(v, __shfl_xor(v, 32)); v = fminf(v, __shfl_xor(v, 16));
  v = fminf(v, __shfl_xor(v, 8));  v = fminf(v, __shfl_xor(v, 4));
  v = fminf(v, __shfl_xor(v, 2));  v = fminf(v, __shfl_xor(v, 1));
  return v;
}

__device__ __forceinline__ float2 f2add(float2 a, float2 b) {
  return make_float2(a.x + b.x, a.y + b.y);
}
// m - s + n
__device__ __forceinline__ float2 f2slide(float2 m, float2 s, float2 n) {
  return make_float2(m.x - s.x + n.x, m.y - s.y + n.y);
}

// 7-tap sliding W-sum over 14 inputs -> 8 outputs (two aligned float4 stores).
#define SLIDE7W8(V, M) do { \
  float s0 = ((V[0]+V[1])+(V[2]+V[3])) + ((V[4]+V[5])+V[6]); \
  float s1 = s0 - V[0] + V[7]; \
  float s2 = s1 - V[1] + V[8]; \
  float s3 = s2 - V[2] + V[9]; \
  float s4 = s3 - V[3] + V[10]; \
  float s5 = s4 - V[4] + V[11]; \
  float s6 = s5 - V[5] + V[12]; \
  float s7 = s6 - V[6] + V[13]; \
  *(float4*)&R[M][rA][c8]     = make_float4(s0, s1, s2, s3); \
  *(float4*)&R[M][rA][c8 + 4] = make_float4(s4, s5, s6, s7); \
} while (0)

// 512 threads = 8 waves; disjoint wave roles:
//   A: tid < 112        (W8 items: rows 0..13 x col-groups 0..7)
//   H: 128 <= tid < 288 (float2 items: ch = (tid-128)>>5, wp = (tid-128)&31)
//   O: all threads, 1 output row each (row = wave)
// (512,2): 256-reg budget -> no spill risk (rounds 2/4 both died on spill).
__global__ __launch_bounds__(512, 2) void ncc_fused(const float* __restrict__ X,
                                                    const float* __restrict__ Y,
                                                    float* __restrict__ part) {
  __shared__ __align__(16) float R[5][14][RP];   // 19.0 KB W-filtered moment rows
  __shared__ __align__(16) float Mh[5][HOT][64]; // 10.2 KB W+H-filtered moments
  __shared__ float red[8][5];

  const int tid = threadIdx.x;
  const int tx = tid & 63, wv = tid >> 6;
  const int wo0 = blockIdx.x * 64;
  const int ho0 = blockIdx.y * HOT;
  const int n   = blockIdx.z / ZCH;
  const int ck  = blockIdx.z % ZCH;
  const int z0  = ck * ZOC;

  const int wo = wo0 + tx;
  const bool act = (wo < WO) && (ho0 + wv < HO);

  const size_t slice = (size_t)HH * WW;
  const float* Xn = X + (size_t)n * DD * slice;
  const float* Yn = Y + (size_t)n * DD * slice;
  const float inv_nw = 1.0f / 343.0f;
  const float LO = -1.0f - 1e-5f, HI = 1.0f + 1e-5f;

  // Phase-A item: 112 items; item p -> row rA=p>>3 (0..13), 8 outputs at cols c8..c8+7.
  const int pA  = tid;
  const bool hasA = (pA < 112);
  const int rA  = pA >> 3;
  const int c8  = (pA & 7) << 3;
  const int hA  = ho0 + rA;
  const int baseW = wo0 + c8;                  // multiple of 8
  const bool okA  = hasA && (hA < HH) && (baseW < WO);
  const bool tail = okA && (baseW + 14 > WW);  // only baseW==152: read 8, zero 6
  const float* XrowA = Xn + (size_t)hA * WW + baseW;
  const float* YrowA = Yn + (size_t)hA * WW + baseW;

  float4 lx0={0,0,0,0}, lx1={0,0,0,0}, lx2={0,0,0,0};
  float4 ly0={0,0,0,0}, ly1={0,0,0,0}, ly2={0,0,0,0};
  float2 lx3={0,0}, ly3={0,0};

  auto loadA = [&](int s_in) {
    if (okA) {
      const float* xp = XrowA + (size_t)(z0 + s_in) * slice;
      const float* yp = YrowA + (size_t)(z0 + s_in) * slice;
      lx0 = *(const float4*)xp;       lx1 = *(const float4*)(xp + 4);
      ly0 = *(const float4*)yp;       ly1 = *(const float4*)(yp + 4);
      if (!tail) {
        lx2 = *(const float4*)(xp + 8); lx3 = *(const float2*)(xp + 12);
        ly2 = *(const float4*)(yp + 8); ly3 = *(const float2*)(yp + 12);
      } else {
        lx2 = make_float4(0.f,0.f,0.f,0.f); lx3 = make_float2(0.f,0.f);
        ly2 = make_float4(0.f,0.f,0.f,0.f); ly3 = make_float2(0.f,0.f);
      }
    }
  };

  auto storeA = [&]() {
    if (okA) {
      const float x[14] = {lx0.x,lx0.y,lx0.z,lx0.w, lx1.x,lx1.y,lx1.z,lx1.w,
                           lx2.x,lx2.y,lx2.z,lx2.w, lx3.x,lx3.y};
      const float y[14] = {ly0.x,ly0.y,ly0.z,ly0.w, ly1.x,ly1.y,ly1.z,ly1.w,
                           ly2.x,ly2.y,ly2.z,ly2.w, ly3.x,ly3.y};
      SLIDE7W8(x, 0);
      SLIDE7W8(y, 1);
      {
        float t[14];
#pragma unroll
        for (int i = 0; i < 14; ++i) t[i] = x[i] * x[i];
        SLIDE7W8(t, 2);
      }
      {
        float t[14];
#pragma unroll
        for (int i = 0; i < 14; ++i) t[i] = y[i] * y[i];
        SLIDE7W8(t, 3);
      }
      {
        float t[14];
#pragma unroll
        for (int i = 0; i < 14; ++i) t[i] = x[i] * y[i];
        SLIDE7W8(t, 4);
      }
    }
  };

  // Phase H (float2): 160 items = (ch 0..4) x (wp 0..31) on tid 128..287.
  // Each item: 14 ds_read_b64 down column-pair 2wp of R (row stride RP/2=34
  // float2), 7-tap slide, 8 ds_write_b64 into Mh (row stride 32 float2).
  // Bank-balanced: offsets 2wp cover all 32 banks exactly 4x per inst = the
  // 512B/inst hardware minimum. Ring live-set = 7 float2 = 14 regs.
  const int idxH = tid - 128;
  const bool okH = (idxH >= 0) && (idxH < 160);
  const int chH = okH ? (idxH >> 5) : 0;
  const int wpH = idxH & 31;
  const float2* rpH = (const float2*)&R[chH][0][wpH << 1];
  float2* mhH = (float2*)&Mh[chH][0][wpH << 1];

  auto phaseH = [&]() {
    if (okH) {
      float2 r0 = rpH[0],       r1 = rpH[34],  r2 = rpH[2*34],
             r3 = rpH[3*34],    r4 = rpH[4*34], r5 = rpH[5*34], r6 = rpH[6*34];
      float2 m = f2add(f2add(f2add(r0, r1), f2add(r2, r3)), f2add(f2add(r4, r5), r6));
      mhH[0] = m;
      float2 nw;
      nw = rpH[7*34];  m = f2slide(m, r0, nw); mhH[32]  = m;
      nw = rpH[8*34];  m = f2slide(m, r1, nw); mhH[64]  = m;
      nw = rpH[9*34];  m = f2slide(m, r2, nw); mhH[96]  = m;
      nw = rpH[10*34]; m = f2slide(m, r3, nw); mhH[128] = m;
      nw = rpH[11*34]; m = f2slide(m, r4, nw); mhH[160] = m;
      nw = rpH[12*34]; m = f2slide(m, r5, nw); mhH[192] = m;
      nw = rpH[13*34]; m = f2slide(m, r6, nw); mhH[224] = m;
    }
  };

  // Sliding-window Z accumulation (single row per thread): 35-float history.
  float zs0=0.f, zs1=0.f, zs2=0.f, zs3=0.f, zs4=0.f;
  float h0[7], h1[7], h2[7], h3[7], h4[7];
#pragma unroll
  for (int j = 0; j < 7; ++j) { h0[j]=0.f; h1[j]=0.f; h2[j]=0.f; h3[j]=0.f; h4[j]=0.f; }
  float p_snv = 0.f, p_sn = 0.f, p_sv = 0.f, p_cnt = 0.f, p_vmin = 3.4e38f;

  loadA(0);
  storeA();
  __syncthreads();

#pragma unroll 1
  for (int sb = 0; sb < NSL; sb += 7) {     // NSL = 28 = 4*7 for EVERY block
#pragma unroll
    for (int u = 0; u < 7; ++u) {
      const int s = sb + u;
      if (s + 1 < NSL) loadA(s + 1);        // global -> regs (stays in flight)
      phaseH();                             // R -> Mh (b64)
      LDS_SYNC();
      {                                     // Phase O: Mh -> sliding-Z + epilogue
        float m0 = Mh[0][wv][tx], m1 = Mh[1][wv][tx], m2 = Mh[2][wv][tx],
              m3 = Mh[3][wv][tx], m4 = Mh[4][wv][tx];
        zs0 += m0 - h0[u]; h0[u] = m0;
        zs1 += m1 - h1[u]; h1[u] = m1;
        zs2 += m2 - h2[u]; h2[u] = m2;
        zs3 += m3 - h3[u]; h3[u] = m3;
        zs4 += m4 - h4[u]; h4[u] = m4;
        if (s >= 6 && act) {
          float num = zs4 - zs0 * zs1 * inv_nw;
          float d0  = zs2 - zs0 * zs0 * inv_nw;
          float d1  = zs3 - zs1 * zs1 * inv_nw;
          float den = d0 * d1;
          if (den > 1e-5f) {
            float ncc = num * __frsqrt_rn(den);
            if (ncc >= LO && ncc <= HI) {
              float v = 0.5f * (d0 + d1);
              p_snv += ncc * v; p_sn += ncc; p_sv += v; p_cnt += 1.f;
              p_vmin = fminf(p_vmin, v);
            }
          }
        }
      }
      if (s + 1 < NSL) storeA();            // vmcnt wait lands HERE
      LDS_SYNC();
    }
  }

  // Wave-level reduction (6 shfl each), then 8 partials through LDS.
  float r0 = wave_sum(p_snv);
  float r1 = wave_sum(p_sn);
  float r2 = wave_sum(p_sv);
  float r3 = wave_sum(p_cnt);
  float r4 = wave_min(p_vmin);
  if (tx == 0) {
    red[wv][0]=r0; red[wv][1]=r1; red[wv][2]=r2; red[wv][3]=r3; red[wv][4]=r4;
  }
  __syncthreads();
  if (tid == 0) {
    float s0=0.f, s1=0.f, s2=0.f, s3=0.f, s4=3.4e38f;
#pragma unroll
    for (int w = 0; w < 8; ++w) {
      s0 += red[w][0]; s1 += red[w][1]; s2 += red[w][2]; s3 += red[w][3];
      s4 = fminf(s4, red[w][4]);
    }
    const int bid = blockIdx.x + NWO * (blockIdx.y + NHO * blockIdx.z);
    float* pp = part + (size_t)bid * 8;
    pp[0] = s0; pp[1] = s1; pp[2] = s2; pp[3] = s3; pp[4] = s4;
  }
}

// Reduce NB per-block partials; loss = 1 - (S_nv - vmin*S_n)/(S_v - vmin*cnt)
// (the min-max weight scale HIGH/(vmax-vmin+1e-12) cancels in w/sum(w)).
__global__ __launch_bounds__(256) void fin(const float* __restrict__ part,
                                           float* __restrict__ out) {
  __shared__ float sm[256];
  const int tid = threadIdx.x;
  float s0 = 0.f, s1 = 0.f, s2 = 0.f, s3 = 0.f, vm = 3.4e38f;
  for (int b = tid; b < NB; b += 256) {
    const float* pp = part + (size_t)b * 8;
    s0 += pp[0]; s1 += pp[1]; s2 += pp[2]; s3 += pp[3];
    vm = fminf(vm, pp[4]);
  }
  s0 = block_sum(s0, sm);
  s1 = block_sum(s1, sm);
  s2 = block_sum(s2, sm);
  s3 = block_sum(s3, sm);
  vm = block_min(vm, sm);
  if (tid == 0) {
    out[0] = 1.0f - (s0 - vm * s1) / (s2 - vm * s3);
  }
}

extern "C" void kernel_launch(void* const* d_in, const int* in_sizes, int n_in,
                              void* d_out, int out_size, void* d_ws, size_t ws_size,
                              hipStream_t stream) {
  const float* X = (const float*)d_in[0];  // y_pred
  const float* Y = (const float*)d_in[1];  // y_true
  // d_in[2]: ones kernel, constant, unused.

  float* part = (float*)d_ws;  // NB * 8 floats = 31.5 KB

  dim3 g(NWO, NHO, NN * ZCH);
  ncc_fused<<<g, 512, 0, stream>>>(X, Y, part);
  fin<<<1, 256, 0, stream>>>(part, (float*)d_out);
}